// Round 4
// baseline (88.691 us; speedup 1.0000x reference)
//
#include <hip/hip_runtime.h>
#include <math.h>

// Problem constants (match reference setup_inputs)
#define B_N   8192      // samples
#define Z_D   128       // feature dim
#define P_N   93        // proxies
#define NCLS  62        // classes
#define A_N   2730      // anchors: arange(0, 8189, 3)
#define BCAP  256       // class-bucket capacity (max expected ~180)
#define GT_S  96        // GT row stride
#define NPART 683       // ceil(A_N / 4) = kB2 grid; 683 = 16*42 + 11
#define TWO_EPS   2e-6f
#define ZEPS2     (128.0f * 1e-6f * 1e-6f)

// R15 == R14 (never measured; container failed twice, likely infra) plus a
// host-side ws_size guard: if the workspace can't hold zT+ps (7.56 MB), fall
// back to the R13-proven legacy kA. Transposed path: kT builds zT[128][8192]
// + pre-scaled proxies ps (+pp/sp, same wave_sum butterfly -> bit-identical);
// kA-P1 then reads z COALESCED (4 lines/instr vs 64) and proxies via
// uniform-address loads (zero LDS in hot loop). Same accumulation
// expressions/order as R0 -> GT bit-identical. kB2 unchanged.

// Relaxed agent-scope ops: coherence-point execution, no cache maintenance
// (R5/R6/R10/R11-validated). Hierarchical counters keep RMW chains <=43 deep.
#define AT_LD(p)      __hip_atomic_load((p), __ATOMIC_RELAXED, __HIP_MEMORY_SCOPE_AGENT)
#define AT_ST(p, v)   __hip_atomic_store((p), (v), __ATOMIC_RELAXED, __HIP_MEMORY_SCOPE_AGENT)
#define AT_ADDU(p, v) __hip_atomic_fetch_add((p), (v), __ATOMIC_RELAXED, __HIP_MEMORY_SCOPE_AGENT)

__device__ __forceinline__ float wave_sum(float v) {
#pragma unroll
  for (int off = 1; off < 64; off <<= 1) v += __shfl_xor(v, off, 64);
  return v;
}
__device__ __forceinline__ float wave_min(float v) {
#pragma unroll
  for (int off = 1; off < 64; off <<= 1) v = fminf(v, __shfl_xor(v, off, 64));
  return v;
}

// --- kT: blocks 0..255 transpose 32 z-rows each into zT[128][8192] via a
// padded LDS tile; blocks 0..92 additionally normalize proxy b (wave 0,
// R0's exact wave_sum layout -> bit-identical pp/sp) and store the scaled
// proxy row to ps. ----------------------------------------------------------
__global__ __launch_bounds__(256) void kT(
    const float* __restrict__ z, const float* __restrict__ prox,
    float* __restrict__ zT, float* __restrict__ ps,
    float* __restrict__ pp, float* __restrict__ sp) {
  __shared__ float4 lds[32][33];           // +1 f4 pad
  const int b = blockIdx.x, tid = threadIdx.x;
  const int j0 = b * 32;
  // read 32 rows x 32 f4, coalesced
#pragma unroll
  for (int k = 0; k < 4; ++k) {
    const int g = tid + k * 256;
    const int r = g >> 5, c = g & 31;
    lds[r][c] = *(const float4*)(z + (size_t)(j0 + r) * Z_D + c * 4);
  }
  __syncthreads();
  const float* ldsF = (const float*)lds;   // row stride 132 floats
#pragma unroll
  for (int k2 = 0; k2 < 4; ++k2) {
    const int idx = tid + k2 * 256;
    const int d = idx >> 3, a = idx & 7;   // d 0..127, a = j-f4 index
    float4 v;
    v.x = ldsF[(4 * a + 0) * 132 + d];
    v.y = ldsF[(4 * a + 1) * 132 + d];
    v.z = ldsF[(4 * a + 2) * 132 + d];
    v.w = ldsF[(4 * a + 3) * 132 + d];
    *(float4*)(zT + (size_t)d * B_N + j0 + 4 * a) = v;  // zT[d][j] = z[j][d]
  }
  // proxy b: norm (R0 layout) + scaled store
  if (b < P_N && tid < 64) {
    const int lane = tid;
    const float a = prox[b * Z_D + lane];
    const float c2 = prox[b * Z_D + 64 + lane];
    const float s = wave_sum(a + c2);
    const float q = wave_sum(a * a + c2 * c2);
    const float inv = 1.0f / fmaxf(sqrtf(q), 1e-12f);
    if (lane == 0) { pp[b] = q * inv * inv; sp[b] = s * inv; }
    if (lane < 32) {
      const float4 v = *(const float4*)(prox + b * Z_D + lane * 4);
      *(float4*)(ps + b * Z_D + lane * 4) =
          make_float4(v.x * inv, v.y * inv, v.z * inv, v.w * inv);
    }
  }
}

// --- kA_t: blocks 0..255 compute GT rows (P1: coalesced zT reads + uniform
// proxy loads, no LDS); blocks 256..317 compact class buckets (P0).
// Accumulation expressions identical to R0 -> bit-identical GT/zz/sz/w. ----
__global__ __launch_bounds__(512) void kA_t(
    const float* __restrict__ zT, const int* __restrict__ y_idx,
    const float* __restrict__ ps, const int* __restrict__ y_map,
    float* __restrict__ zz, float* __restrict__ sz, float* __restrict__ w,
    int* __restrict__ cnt, int* __restrict__ bkt, float* __restrict__ GT,
    unsigned int* __restrict__ ctr) {
  __shared__ int lcnt;
  const int b = blockIdx.x, tid = threadIdx.x;

  if (b == 0 && tid < 17) ctr[tid * 32] = 0u;  // visible to kB2 via boundary

  if (b < 256) {
    // --- P1: 16 j-chunks x 512 rows (1 row/thread), 16 k-tiles.
    const int jch = b & 15, kt = b >> 4, k0 = kt * 6;
    const int j = jch * 512 + tid;
    const float* __restrict__ zc = zT + j;           // column j of z
    const float* __restrict__ p0 = ps + (size_t)k0 * Z_D;
    if (kt < 15) {
      float a0 = 0, a1 = 0, a2 = 0, a3 = 0, a4 = 0, a5 = 0;
#pragma unroll 8
      for (int g = 0; g < 32; ++g) {
        const float zv0 = zc[(size_t)(4 * g + 0) * B_N];  // coalesced
        const float zv1 = zc[(size_t)(4 * g + 1) * B_N];
        const float zv2 = zc[(size_t)(4 * g + 2) * B_N];
        const float zv3 = zc[(size_t)(4 * g + 3) * B_N];
        const float4 q0 = *(const float4*)(p0 + 0 * Z_D + 4 * g);  // uniform
        const float4 q1 = *(const float4*)(p0 + 1 * Z_D + 4 * g);
        const float4 q2 = *(const float4*)(p0 + 2 * Z_D + 4 * g);
        const float4 q3 = *(const float4*)(p0 + 3 * Z_D + 4 * g);
        const float4 q4 = *(const float4*)(p0 + 4 * Z_D + 4 * g);
        const float4 q5 = *(const float4*)(p0 + 5 * Z_D + 4 * g);
        a0 += zv0 * q0.x + zv1 * q0.y + zv2 * q0.z + zv3 * q0.w;
        a1 += zv0 * q1.x + zv1 * q1.y + zv2 * q1.z + zv3 * q1.w;
        a2 += zv0 * q2.x + zv1 * q2.y + zv2 * q2.z + zv3 * q2.w;
        a3 += zv0 * q3.x + zv1 * q3.y + zv2 * q3.z + zv3 * q3.w;
        a4 += zv0 * q4.x + zv1 * q4.y + zv2 * q4.z + zv3 * q4.w;
        a5 += zv0 * q5.x + zv1 * q5.y + zv2 * q5.z + zv3 * q5.w;
      }
      float* g = GT + (size_t)j * GT_S + k0;       // k0 even -> 8B aligned
      *(float2*)(g + 0) = make_float2(a0, a1);
      *(float2*)(g + 2) = make_float2(a2, a3);
      *(float2*)(g + 4) = make_float2(a4, a5);
    } else {
      float a0 = 0, a1 = 0, a2 = 0, zs = 0, zq = 0;
#pragma unroll 8
      for (int g = 0; g < 32; ++g) {
        const float zv0 = zc[(size_t)(4 * g + 0) * B_N];
        const float zv1 = zc[(size_t)(4 * g + 1) * B_N];
        const float zv2 = zc[(size_t)(4 * g + 2) * B_N];
        const float zv3 = zc[(size_t)(4 * g + 3) * B_N];
        const float4 q0 = *(const float4*)(p0 + 0 * Z_D + 4 * g);
        const float4 q1 = *(const float4*)(p0 + 1 * Z_D + 4 * g);
        const float4 q2 = *(const float4*)(p0 + 2 * Z_D + 4 * g);
        zs += zv0 + zv1 + zv2 + zv3;
        zq += zv0 * zv0 + zv1 * zv1 + zv2 * zv2 + zv3 * zv3;
        a0 += zv0 * q0.x + zv1 * q0.y + zv2 * q0.z + zv3 * q0.w;
        a1 += zv0 * q1.x + zv1 * q1.y + zv2 * q1.z + zv3 * q1.w;
        a2 += zv0 * q2.x + zv1 * q2.y + zv2 * q2.z + zv3 * q2.w;
      }
      float* g = GT + (size_t)j * GT_S + 90;       // 90 even -> 8B aligned
      *(float2*)(g) = make_float2(a0, a1);
      g[2] = a2;
      zz[j] = zq;
      sz[j] = zs;
      w[j] = zq - TWO_EPS * zs;            // per-j part of pdist(prox, z)
    }
  } else {
    // --- P0: class c = b-256 compacts its sample indices (y_map unique).
    const int c = b - 256;
    if (tid == 0) lcnt = 0;
    __syncthreads();
    const int ym = y_map[c];
    for (int j = tid; j < B_N; j += 512) {
      if (y_idx[j] == ym) {
        const int pos = atomicAdd(&lcnt, 1);     // LDS atomic
        if (pos < BCAP) bkt[c * BCAP + pos] = j;
      }
    }
    __syncthreads();
    if (tid == 0) cnt[c] = min(lcnt, BCAP);
  }
}

// --- kA_l: legacy R13 path (LDS-staged proxy tile), used only when ws_size
// can't hold zT. Bit-identical outputs to kA_t. ----------------------------
__global__ __launch_bounds__(512) void kA_l(
    const float* __restrict__ z, const int* __restrict__ y_idx,
    const float* __restrict__ prox, const int* __restrict__ y_map,
    float* __restrict__ pp, float* __restrict__ sp,
    float* __restrict__ zz, float* __restrict__ sz, float* __restrict__ w,
    int* __restrict__ cnt, int* __restrict__ bkt, float* __restrict__ GT,
    unsigned int* __restrict__ ctr) {
  __shared__ float linv[6];
  __shared__ float pt[6 * Z_D];
  __shared__ int lcnt;
  const int b = blockIdx.x, tid = threadIdx.x;
  const int lane = tid & 63, wv = tid >> 6;

  if (b == 0 && tid < 17) ctr[tid * 32] = 0u;

  if (b < 256) {
    const int jch = b & 15, kt = b >> 4, k0 = kt * 6;
    const int nk = (kt == 15) ? 3 : 6;
    const int j = jch * 512 + tid;
    const float* __restrict__ zrow = z + (size_t)j * Z_D;
    if (wv < nk) {
      const int k = k0 + wv;
      const float a = prox[k * Z_D + lane];
      const float c = prox[k * Z_D + 64 + lane];
      const float s = wave_sum(a + c);
      const float q = wave_sum(a * a + c * c);
      const float inv = 1.0f / fmaxf(sqrtf(q), 1e-12f);
      if (lane == 0) {
        linv[wv] = inv;
        if (jch == 0) { pp[k] = q * inv * inv; sp[k] = s * inv; }
      }
    }
    __syncthreads();
    {
      const int nf = nk * 32;
      const float4* __restrict__ src = (const float4*)(prox + (size_t)k0 * Z_D);
      for (int t = tid; t < nf; t += 512) {
        const float iv = linv[t >> 5];
        const float4 v = src[t];
        ((float4*)pt)[t] = make_float4(v.x * iv, v.y * iv, v.z * iv, v.w * iv);
      }
    }
    __syncthreads();
    if (kt < 15) {
      float a0 = 0, a1 = 0, a2 = 0, a3 = 0, a4 = 0, a5 = 0;
#pragma unroll 8
      for (int i4 = 0; i4 < Z_D; i4 += 4) {
        const float4 zv = *(const float4*)(zrow + i4);
        const int f = i4 >> 2;
        const float4 q0 = ((const float4*)pt)[0 * 32 + f];
        const float4 q1 = ((const float4*)pt)[1 * 32 + f];
        const float4 q2 = ((const float4*)pt)[2 * 32 + f];
        const float4 q3 = ((const float4*)pt)[3 * 32 + f];
        const float4 q4 = ((const float4*)pt)[4 * 32 + f];
        const float4 q5 = ((const float4*)pt)[5 * 32 + f];
        a0 += zv.x * q0.x + zv.y * q0.y + zv.z * q0.z + zv.w * q0.w;
        a1 += zv.x * q1.x + zv.y * q1.y + zv.z * q1.z + zv.w * q1.w;
        a2 += zv.x * q2.x + zv.y * q2.y + zv.z * q2.z + zv.w * q2.w;
        a3 += zv.x * q3.x + zv.y * q3.y + zv.z * q3.z + zv.w * q3.w;
        a4 += zv.x * q4.x + zv.y * q4.y + zv.z * q4.z + zv.w * q4.w;
        a5 += zv.x * q5.x + zv.y * q5.y + zv.z * q5.z + zv.w * q5.w;
      }
      float* g = GT + (size_t)j * GT_S + k0;
      *(float2*)(g + 0) = make_float2(a0, a1);
      *(float2*)(g + 2) = make_float2(a2, a3);
      *(float2*)(g + 4) = make_float2(a4, a5);
    } else {
      float a0 = 0, a1 = 0, a2 = 0, zs = 0, zq = 0;
#pragma unroll 8
      for (int i4 = 0; i4 < Z_D; i4 += 4) {
        const float4 zv = *(const float4*)(zrow + i4);
        const int f = i4 >> 2;
        const float4 q0 = ((const float4*)pt)[0 * 32 + f];
        const float4 q1 = ((const float4*)pt)[1 * 32 + f];
        const float4 q2 = ((const float4*)pt)[2 * 32 + f];
        zs += zv.x + zv.y + zv.z + zv.w;
        zq += zv.x * zv.x + zv.y * zv.y + zv.z * zv.z + zv.w * zv.w;
        a0 += zv.x * q0.x + zv.y * q0.y + zv.z * q0.z + zv.w * q0.w;
        a1 += zv.x * q1.x + zv.y * q1.y + zv.z * q1.z + zv.w * q1.w;
        a2 += zv.x * q2.x + zv.y * q2.y + zv.z * q2.z + zv.w * q2.w;
      }
      float* g = GT + (size_t)j * GT_S + 90;
      *(float2*)(g) = make_float2(a0, a1);
      g[2] = a2;
      zz[j] = zq;
      sz[j] = zs;
      w[j] = zq - TWO_EPS * zs;
    }
  } else {
    const int c = b - 256;
    if (tid == 0) lcnt = 0;
    __syncthreads();
    const int ym = y_map[c];
    for (int j = tid; j < B_N; j += 512) {
      if (y_idx[j] == ym) {
        const int pos = atomicAdd(&lcnt, 1);
        if (pos < BCAP) bkt[c * BCAP + pos] = j;
      }
    }
    __syncthreads();
    if (tid == 0) cnt[c] = min(lcnt, BCAP);
  }
}

// --- kB2: one wave per anchor (R6-validated step-b w-gather shape);
// R10/R11-validated hierarchical finalize. R13's early cnt/bkt/w issue kept
// (neutral). Candidate set, guards & tie-breaks identical to R0. -----------
__global__ __launch_bounds__(256) void kB2(
    const int* __restrict__ y_idx, const int* __restrict__ y_map,
    const float* __restrict__ pp, const float* __restrict__ sp,
    const float* __restrict__ zz, const float* __restrict__ sz,
    const float* __restrict__ w,
    const int* __restrict__ cnt, const int* __restrict__ bkt,
    const float* __restrict__ GT, float* partial, unsigned int* ctr,
    float* __restrict__ out) {
  __shared__ float lpp[P_N], lsp[P_N];
  __shared__ int lymap[NCLS];
  __shared__ float part[4];
  const int b = blockIdx.x;
  const int tid = threadIdx.x, lane = tid & 63, wv = tid >> 6;
  if (tid < P_N) { lpp[tid] = pp[tid]; lsp[tid] = sp[tid]; }
  if (tid < NCLS) lymap[tid] = y_map[tid];
  __syncthreads();

  const int wid = b * 4 + wv;
  float loss = 0.0f;
  if (wid < A_N) {
    const int i = 3 * wid;
    const int yi = y_idx[i];
    const unsigned long long mm = __ballot(lane < NCLS && lymap[lane] == yi);
    const int cls = __ffsll(mm) - 1;       // unique match (y_map unique)
    const float zzi = zz[i], szi = sz[i];
    const int kB = lane + 64;

    // early issue: class bucket + w gathers (independent of step a's result)
    const int n = cnt[cls];
    const int* __restrict__ bk = bkt + cls * BCAP;
    int pjj[4];
    float pww[4];
#pragma unroll
    for (int r = 0; r < 4; ++r) {
      const int t = lane + (r << 6);
      pjj[r] = (t < n) ? bk[t] : -1;       // -1 => excluded (i >= 0)
    }
#pragma unroll
    for (int r = 0; r < 4; ++r)
      pww[r] = (pjj[r] >= i) ? w[pjj[r]] : 0.0f;  // exec-masked gather

    // step a: nearest proxy (argmin, first-index tie-break)
    const float* __restrict__ GTi = GT + (size_t)i * GT_S;
    float v1 = fmaxf(zzi + lpp[lane] - 2.0f * GTi[lane] +
                     TWO_EPS * (szi - lsp[lane]) + ZEPS2, 0.0f);
    int i1 = lane;
    if (kB < P_N) {
      const float v2 = fmaxf(zzi + lpp[kB] - 2.0f * GTi[kB] +
                             TWO_EPS * (szi - lsp[kB]) + ZEPS2, 0.0f);
      if (v2 < v1) { v1 = v2; i1 = kB; }
    }
#pragma unroll
    for (int off = 1; off < 64; off <<= 1) {
      const float ov = __shfl_xor(v1, off, 64);
      const int oi = __shfl_xor(i1, off, 64);
      if (ov < v1 || (ov == v1 && oi < i1)) { v1 = ov; i1 = oi; }
    }
    const int p = i1;

    // step b: hardest positive in same-class suffix (prefetched candidates;
    // only the GT[jj*96+p] gather waits on p)
    const float cp = lpp[p] + TWO_EPS * lsp[p] + ZEPS2;
    float best = -INFINITY;
    int bestj = 0x7fffffff;
#pragma unroll
    for (int r = 0; r < 4; ++r) {
      const int jj = pjj[r];
      if (jj >= i) {
        const float vv = fmaxf(cp + pww[r] - 2.0f * GT[(size_t)jj * GT_S + p], 0.0f);
        if (vv > best || (vv == best && jj < bestj)) { best = vv; bestj = jj; }
      }
    }
#pragma unroll
    for (int off = 1; off < 64; off <<= 1) {
      const float ov = __shfl_xor(best, off, 64);
      const int oj = __shfl_xor(bestj, off, 64);
      if (ov > best || (ov == best && oj < bestj)) { best = ov; bestj = oj; }
    }
    const float Dp = sqrtf(best);
    const int jp = bestj;

    // step c: logsumexp(-D_n) over proxies
    const float zzj = zz[jp], szj = sz[jp];
    const float* __restrict__ GTj = GT + (size_t)jp * GT_S;
    const float d1 = sqrtf(fmaxf(zzj + lpp[lane] - 2.0f * GTj[lane] +
                                 TWO_EPS * (szj - lsp[lane]) + ZEPS2, 0.0f));
    float d2 = INFINITY;
    if (kB < P_N)
      d2 = sqrtf(fmaxf(zzj + lpp[kB] - 2.0f * GTj[kB] +
                       TWO_EPS * (szj - lsp[kB]) + ZEPS2, 0.0f));
    const float mn = wave_min(fminf(d1, d2));
    float ss = expf(mn - d1) + ((kB < P_N) ? expf(mn - d2) : 0.0f);
    ss = wave_sum(ss);
    loss = Dp - mn + logf(ss);
  }
  if (lane == 0) part[wv] = (wid < A_N) ? loss : 0.0f;
  __syncthreads();

  // finalize (R10/R11-validated): distinct-address partial store -> drain ->
  // sub-counter RMW (<=43 deep); sub closer bumps super; last block's wave 0
  // reduces all 683 partials. Waves 1-3 retire immediately.
  if (wv == 0) {
    int last = 0;
    if (lane == 0) {
      AT_ST(&partial[b], part[0] + part[1] + part[2] + part[3]);
      __builtin_amdgcn_s_waitcnt(0);       // store completed at LLC
      const int sub = b & 15;              // residues 0..10: 43; 11..15: 42
      const unsigned quota = (sub < 11) ? 43u : 42u;
      const unsigned old = AT_ADDU(&ctr[sub * 32], 1u);
      if (old == quota - 1u) {
        const unsigned so = AT_ADDU(&ctr[16 * 32], 1u);
        if (so == 15u) last = 1;
      }
    }
    last = __shfl(last, 0, 64);
    if (last) {                            // one wave reduces 683 partials
      float s = 0.0f;
#pragma unroll
      for (int r = 0; r < 11; ++r) {
        const int t = lane + r * 64;
        if (t < NPART) s += AT_LD(&partial[t]);
      }
      s = wave_sum(s);
      if (lane == 0) out[0] = s * (1.0f / (float)A_N);
    }
  }
}

extern "C" void kernel_launch(void* const* d_in, const int* in_sizes, int n_in,
                              void* d_out, int out_size, void* d_ws, size_t ws_size,
                              hipStream_t stream) {
  const float* z = (const float*)d_in[0];      // [8192,128] f32
  const int* y_idx = (const int*)d_in[1];      // [8192] i32
  const float* prox = (const float*)d_in[2];   // [93,128] f32
  const int* y_map = (const int*)d_in[3];      // [62] i32
  float* out = (float*)d_out;

  // workspace layout (bytes); transposed path needs 7.56 MB total
  char* ws = (char*)d_ws;
  unsigned int* ctr = (unsigned int*)(ws + 0); // 17 counters, 128B stride
  float* pp    = (float*)(ws + 2560);          // 93*4 (pad 512)
  float* sp    = (float*)(ws + 3072);          // 93*4 (pad 512) -> 3584
  float* zz    = (float*)(ws + 3584);          // 8192*4 -> 36352
  float* sz    = (float*)(ws + 36352);         // -> 69120
  float* w     = (float*)(ws + 69120);         // -> 101888
  int*   cnt   = (int*)  (ws + 101888);        // 62*4 (pad 256) -> 102144
  int*   bkt   = (int*)  (ws + 102144);        // 62*256*4 -> 165632
  float* parts = (float*)(ws + 165632);        // 683*4 (pad) -> 168448
  float* GT    = (float*)(ws + 168448);        // 8192*96*4 -> 3314176
  float* zT    = (float*)(ws + 3314176);       // 128*8192*4 -> 7508480
  float* psc   = (float*)(ws + 7508480);       // 93*128*4 -> 7556096

  if (ws_size >= (size_t)7556096) {
    kT<<<256, 256, 0, stream>>>(z, prox, zT, psc, pp, sp);
    kA_t<<<256 + NCLS, 512, 0, stream>>>(zT, y_idx, psc, y_map,
                                         zz, sz, w, cnt, bkt, GT, ctr);
  } else {
    kA_l<<<256 + NCLS, 512, 0, stream>>>(z, y_idx, prox, y_map, pp, sp,
                                         zz, sz, w, cnt, bkt, GT, ctr);
  }
  kB2<<<NPART, 256, 0, stream>>>(y_idx, y_map, pp, sp, zz, sz, w,
                                 cnt, bkt, GT, parts, ctr, out);
}

// Round 6
// 82.831 us; speedup vs baseline: 1.0707x; 1.0707x over previous
//
#include <hip/hip_runtime.h>
#include <math.h>

// Problem constants (match reference setup_inputs)
#define B_N   8192      // samples
#define Z_D   128       // feature dim
#define P_N   93        // proxies
#define NCLS  62        // classes
#define A_N   2730      // anchors: arange(0, 8189, 3)
#define BCAP  256       // class-bucket capacity (max expected ~180)
#define GT_S  96        // GT row stride
#define NPART 683       // ceil(A_N / 4) = kB2 grid; 683 = 16*42 + 11
#define TWO_EPS   2e-6f
#define ZEPS2     (128.0f * 1e-6f * 1e-6f)

// R17 == R16 (resubmit: container failed twice on a kernel that already
// passed twice at 81.4/81.5 us -> infra flake, not kernel). Ledger:
//   R0  (this structure)            81.38
//   R2  (+kB2 early-hoist)          81.53  (hoist neutral -> dropped)
//   R12 (kA 256-thr, grid 256)      84.78  (occupancy collapse)
//   R15 (kT + transposed kA)        88.69  (extra launch + slower kA_t)
// Both "theoretically better" kA restructures regressed; keep the
// twice-validated shape.

// Relaxed agent-scope ops: coherence-point execution, no cache maintenance
// (R5/R6/R10/R11-validated). Hierarchical counters keep RMW chains <=43 deep.
#define AT_LD(p)      __hip_atomic_load((p), __ATOMIC_RELAXED, __HIP_MEMORY_SCOPE_AGENT)
#define AT_ST(p, v)   __hip_atomic_store((p), (v), __ATOMIC_RELAXED, __HIP_MEMORY_SCOPE_AGENT)
#define AT_ADDU(p, v) __hip_atomic_fetch_add((p), (v), __ATOMIC_RELAXED, __HIP_MEMORY_SCOPE_AGENT)

__device__ __forceinline__ float wave_sum(float v) {
#pragma unroll
  for (int off = 1; off < 64; off <<= 1) v += __shfl_xor(v, off, 64);
  return v;
}
__device__ __forceinline__ float wave_min(float v) {
#pragma unroll
  for (int off = 1; off < 64; off <<= 1) v = fminf(v, __shfl_xor(v, off, 64));
  return v;
}

// --- kA: blocks 0..255 compute GT rows (P1, LDS-staged pre-scaled proxy
// tile, 1 row/thread); blocks 256..317 compact class index buckets (P0, no
// member reductions — w[] comes from P1 tile 15). Kernel boundary = barrier.
__global__ __launch_bounds__(512) void kA(
    const float* __restrict__ z, const int* __restrict__ y_idx,
    const float* __restrict__ prox, const int* __restrict__ y_map,
    float* __restrict__ pp, float* __restrict__ sp,
    float* __restrict__ zz, float* __restrict__ sz, float* __restrict__ w,
    int* __restrict__ cnt, int* __restrict__ bkt, float* __restrict__ GT,
    unsigned int* __restrict__ ctr) {
  __shared__ float linv[6];
  __shared__ float pt[6 * Z_D];            // pre-scaled proxy tile (3 KB)
  __shared__ int lcnt;
  const int b = blockIdx.x, tid = threadIdx.x;
  const int lane = tid & 63, wv = tid >> 6;

  if (b == 0 && tid < 17) ctr[tid * 32] = 0u;  // visible to kB2 via boundary

  if (b < 256) {
    // --- P1: 16 j-chunks x 512 rows (1 row/thread), 16 k-tiles.
    // Tiles 0..14: 6 proxies; tile 15: proxies 90..92 + z row stats + w.
    const int jch = b & 15, kt = b >> 4, k0 = kt * 6;
    const int nk = (kt == 15) ? 3 : 6;
    const int j = jch * 512 + tid;
    const float* __restrict__ zrow = z + (size_t)j * Z_D;
    if (wv < nk) {                         // per-proxy norm via wave reduce
      const int k = k0 + wv;
      const float a = prox[k * Z_D + lane];
      const float c = prox[k * Z_D + 64 + lane];
      const float s = wave_sum(a + c);
      const float q = wave_sum(a * a + c * c);
      const float inv = 1.0f / fmaxf(sqrtf(q), 1e-12f);
      if (lane == 0) {
        linv[wv] = inv;
        if (jch == 0) { pp[k] = q * inv * inv; sp[k] = s * inv; }
      }
    }
    __syncthreads();
    // stage tile into LDS, pre-scaled by inv-norm (t>>5 = row, 32 f4/row)
    {
      const int nf = nk * 32;
      const float4* __restrict__ src = (const float4*)(prox + (size_t)k0 * Z_D);
      for (int t = tid; t < nf; t += 512) {
        const float iv = linv[t >> 5];
        const float4 v = src[t];
        ((float4*)pt)[t] = make_float4(v.x * iv, v.y * iv, v.z * iv, v.w * iv);
      }
    }
    __syncthreads();
    if (kt < 15) {
      float a0 = 0, a1 = 0, a2 = 0, a3 = 0, a4 = 0, a5 = 0;
#pragma unroll 8
      for (int i4 = 0; i4 < Z_D; i4 += 4) {
        const float4 zv = *(const float4*)(zrow + i4);
        const int f = i4 >> 2;
        const float4 q0 = ((const float4*)pt)[0 * 32 + f];  // LDS broadcast
        const float4 q1 = ((const float4*)pt)[1 * 32 + f];
        const float4 q2 = ((const float4*)pt)[2 * 32 + f];
        const float4 q3 = ((const float4*)pt)[3 * 32 + f];
        const float4 q4 = ((const float4*)pt)[4 * 32 + f];
        const float4 q5 = ((const float4*)pt)[5 * 32 + f];
        a0 += zv.x * q0.x + zv.y * q0.y + zv.z * q0.z + zv.w * q0.w;
        a1 += zv.x * q1.x + zv.y * q1.y + zv.z * q1.z + zv.w * q1.w;
        a2 += zv.x * q2.x + zv.y * q2.y + zv.z * q2.z + zv.w * q2.w;
        a3 += zv.x * q3.x + zv.y * q3.y + zv.z * q3.z + zv.w * q3.w;
        a4 += zv.x * q4.x + zv.y * q4.y + zv.z * q4.z + zv.w * q4.w;
        a5 += zv.x * q5.x + zv.y * q5.y + zv.z * q5.z + zv.w * q5.w;
      }
      float* g = GT + (size_t)j * GT_S + k0;       // k0 even -> 8B aligned
      *(float2*)(g + 0) = make_float2(a0, a1);
      *(float2*)(g + 2) = make_float2(a2, a3);
      *(float2*)(g + 4) = make_float2(a4, a5);
    } else {
      float a0 = 0, a1 = 0, a2 = 0, zs = 0, zq = 0;
#pragma unroll 8
      for (int i4 = 0; i4 < Z_D; i4 += 4) {
        const float4 zv = *(const float4*)(zrow + i4);
        const int f = i4 >> 2;
        const float4 q0 = ((const float4*)pt)[0 * 32 + f];
        const float4 q1 = ((const float4*)pt)[1 * 32 + f];
        const float4 q2 = ((const float4*)pt)[2 * 32 + f];
        zs += zv.x + zv.y + zv.z + zv.w;
        zq += zv.x * zv.x + zv.y * zv.y + zv.z * zv.z + zv.w * zv.w;
        a0 += zv.x * q0.x + zv.y * q0.y + zv.z * q0.z + zv.w * q0.w;
        a1 += zv.x * q1.x + zv.y * q1.y + zv.z * q1.z + zv.w * q1.w;
        a2 += zv.x * q2.x + zv.y * q2.y + zv.z * q2.z + zv.w * q2.w;
      }
      float* g = GT + (size_t)j * GT_S + 90;       // 90 even -> 8B aligned
      *(float2*)(g) = make_float2(a0, a1);
      g[2] = a2;
      zz[j] = zq;
      sz[j] = zs;
      w[j] = zq - TWO_EPS * zs;            // per-j part of pdist(prox, z)
    }
  } else {
    // --- P0: class c = b-256 compacts its sample indices (y_map unique).
    // No per-member math — kB2 gathers w[jj] (computed by P1 tile 15).
    const int c = b - 256;
    if (tid == 0) lcnt = 0;
    __syncthreads();
    const int ym = y_map[c];
    for (int j = tid; j < B_N; j += 512) {
      if (y_idx[j] == ym) {
        const int pos = atomicAdd(&lcnt, 1);     // LDS atomic
        if (pos < BCAP) bkt[c * BCAP + pos] = j;
      }
    }
    __syncthreads();
    if (tid == 0) cnt[c] = min(lcnt, BCAP);
  }
}

// --- kB2: one wave per anchor (R6-validated step-b w-gather shape);
// R10/R11-validated hierarchical finalize. ----------------------------------
__global__ __launch_bounds__(256) void kB2(
    const int* __restrict__ y_idx, const int* __restrict__ y_map,
    const float* __restrict__ pp, const float* __restrict__ sp,
    const float* __restrict__ zz, const float* __restrict__ sz,
    const float* __restrict__ w,
    const int* __restrict__ cnt, const int* __restrict__ bkt,
    const float* __restrict__ GT, float* partial, unsigned int* ctr,
    float* __restrict__ out) {
  __shared__ float lpp[P_N], lsp[P_N];
  __shared__ int lymap[NCLS];
  __shared__ float part[4];
  const int b = blockIdx.x;
  const int tid = threadIdx.x, lane = tid & 63, wv = tid >> 6;
  if (tid < P_N) { lpp[tid] = pp[tid]; lsp[tid] = sp[tid]; }
  if (tid < NCLS) lymap[tid] = y_map[tid];
  __syncthreads();

  const int wid = b * 4 + wv;
  float loss = 0.0f;
  if (wid < A_N) {
    const int i = 3 * wid;
    const int yi = y_idx[i];
    const unsigned long long mm = __ballot(lane < NCLS && lymap[lane] == yi);
    const int cls = __ffsll(mm) - 1;       // unique match (y_map unique)
    const float zzi = zz[i], szi = sz[i];
    const int kB = lane + 64;

    // step a: nearest proxy (argmin, first-index tie-break)
    const float* __restrict__ GTi = GT + (size_t)i * GT_S;
    float v1 = fmaxf(zzi + lpp[lane] - 2.0f * GTi[lane] +
                     TWO_EPS * (szi - lsp[lane]) + ZEPS2, 0.0f);
    int i1 = lane;
    if (kB < P_N) {
      const float v2 = fmaxf(zzi + lpp[kB] - 2.0f * GTi[kB] +
                             TWO_EPS * (szi - lsp[kB]) + ZEPS2, 0.0f);
      if (v2 < v1) { v1 = v2; i1 = kB; }
    }
#pragma unroll
    for (int off = 1; off < 64; off <<= 1) {
      const float ov = __shfl_xor(v1, off, 64);
      const int oi = __shfl_xor(i1, off, 64);
      if (ov < v1 || (ov == v1 && oi < i1)) { v1 = ov; i1 = oi; }
    }
    const int p = i1;

    // step b: hardest positive in same-class suffix (w-gather, R6 shape)
    const float cp = lpp[p] + TWO_EPS * lsp[p] + ZEPS2;
    const int n = cnt[cls];
    const int* __restrict__ bk = bkt + cls * BCAP;
    float best = -INFINITY;
    int bestj = 0x7fffffff;
    for (int t = lane; t < n; t += 64) {
      const int jj = bk[t];
      if (jj >= i) {
        const float vv = fmaxf(cp + w[jj] - 2.0f * GT[(size_t)jj * GT_S + p], 0.0f);
        if (vv > best || (vv == best && jj < bestj)) { best = vv; bestj = jj; }
      }
    }
#pragma unroll
    for (int off = 1; off < 64; off <<= 1) {
      const float ov = __shfl_xor(best, off, 64);
      const int oj = __shfl_xor(bestj, off, 64);
      if (ov > best || (ov == best && oj < bestj)) { best = ov; bestj = oj; }
    }
    const float Dp = sqrtf(best);
    const int jp = bestj;

    // step c: logsumexp(-D_n) over proxies
    const float zzj = zz[jp], szj = sz[jp];
    const float* __restrict__ GTj = GT + (size_t)jp * GT_S;
    const float d1 = sqrtf(fmaxf(zzj + lpp[lane] - 2.0f * GTj[lane] +
                                 TWO_EPS * (szj - lsp[lane]) + ZEPS2, 0.0f));
    float d2 = INFINITY;
    if (kB < P_N)
      d2 = sqrtf(fmaxf(zzj + lpp[kB] - 2.0f * GTj[kB] +
                       TWO_EPS * (szj - lsp[kB]) + ZEPS2, 0.0f));
    const float mn = wave_min(fminf(d1, d2));
    float ss = expf(mn - d1) + ((kB < P_N) ? expf(mn - d2) : 0.0f);
    ss = wave_sum(ss);
    loss = Dp - mn + logf(ss);
  }
  if (lane == 0) part[wv] = (wid < A_N) ? loss : 0.0f;
  __syncthreads();

  // finalize (R10/R11-validated): distinct-address partial store -> drain ->
  // sub-counter RMW (<=43 deep); sub closer bumps super; last block's wave 0
  // reduces all 683 partials. Waves 1-3 retire immediately.
  if (wv == 0) {
    int last = 0;
    if (lane == 0) {
      AT_ST(&partial[b], part[0] + part[1] + part[2] + part[3]);
      __builtin_amdgcn_s_waitcnt(0);       // store completed at LLC
      const int sub = b & 15;              // residues 0..10: 43; 11..15: 42
      const unsigned quota = (sub < 11) ? 43u : 42u;
      const unsigned old = AT_ADDU(&ctr[sub * 32], 1u);
      if (old == quota - 1u) {
        const unsigned so = AT_ADDU(&ctr[16 * 32], 1u);
        if (so == 15u) last = 1;
      }
    }
    last = __shfl(last, 0, 64);
    if (last) {                            // one wave reduces 683 partials
      float s = 0.0f;
#pragma unroll
      for (int r = 0; r < 11; ++r) {
        const int t = lane + r * 64;
        if (t < NPART) s += AT_LD(&partial[t]);
      }
      s = wave_sum(s);
      if (lane == 0) out[0] = s * (1.0f / (float)A_N);
    }
  }
}

extern "C" void kernel_launch(void* const* d_in, const int* in_sizes, int n_in,
                              void* d_out, int out_size, void* d_ws, size_t ws_size,
                              hipStream_t stream) {
  const float* z = (const float*)d_in[0];      // [8192,128] f32
  const int* y_idx = (const int*)d_in[1];      // [8192] i32
  const float* prox = (const float*)d_in[2];   // [93,128] f32
  const int* y_map = (const int*)d_in[3];      // [62] i32
  float* out = (float*)d_out;

  // workspace layout (bytes), ~3.31 MB
  char* ws = (char*)d_ws;
  unsigned int* ctr = (unsigned int*)(ws + 0); // 17 counters, 128B stride
  float* pp    = (float*)(ws + 2560);          // 93*4 (pad 512)
  float* sp    = (float*)(ws + 3072);          // 93*4 (pad 512) -> 3584
  float* zz    = (float*)(ws + 3584);          // 8192*4 -> 36352
  float* sz    = (float*)(ws + 36352);         // -> 69120
  float* w     = (float*)(ws + 69120);         // -> 101888
  int*   cnt   = (int*)  (ws + 101888);        // 62*4 (pad 256) -> 102144
  int*   bkt   = (int*)  (ws + 102144);        // 62*256*4 -> 165632
  float* parts = (float*)(ws + 165632);        // 683*4 (pad) -> 168448
  float* GT    = (float*)(ws + 168448);        // 8192*96*4 -> 3314176

  kA<<<256 + NCLS, 512, 0, stream>>>(z, y_idx, prox, y_map,
                                     pp, sp, zz, sz, w, cnt, bkt, GT, ctr);
  kB2<<<NPART, 256, 0, stream>>>(y_idx, y_map, pp, sp, zz, sz, w,
                                 cnt, bkt, GT, parts, ctr, out);
}